// Round 11
// baseline (97.435 us; speedup 1.0000x reference)
//
#include <hip/hip_runtime.h>
#include <hip/hip_bf16.h>

#define B_ 16
#define T_ 2048
#define C_ 1024
#define HD_ 64

typedef __attribute__((ext_vector_type(8))) short bf16x8;
typedef __attribute__((ext_vector_type(4))) float f32x4;

__device__ __forceinline__ unsigned short f2bf(float f) {
  return __builtin_bit_cast(unsigned short, __float2bfloat16(f));
}

// ---- W convert: per-K-step tiles w3[kk][n] (kk=0..15, 24KB tiles) ----
// n: row = n>>6 (192 rows = output col), chunk c=(n>>3)&7, e=n&7.
// Logical k = kk*64 + ((c ^ (row&7))*8 + e); m = row>>6, d = row&63.
// Scale 1/sqrt(C)*log2(e) folded into Wk -> scores in exp2 domain.
__global__ void wconv_kernel(const float* __restrict__ Wk, const float* __restrict__ Wq,
                             const float* __restrict__ Wv, unsigned short* __restrict__ w3) {
  int o = blockIdx.x * 256 + threadIdx.x;   // 16*12288 = 196608 total
  if (o >= 16 * 12288) return;
  int kk = o / 12288;
  int n = o - kk * 12288;
  int row = n >> 6;
  int c = (n >> 3) & 7;
  int e = n & 7;
  int k = kk * 64 + (((c ^ (row & 7)) << 3) | e);
  int m = row >> 6, d = row & 63;
  const float* W = (m == 0) ? Wk : (m == 1) ? Wq : Wv;
  float v = W[k * HD_ + d];
  if (m == 0) v *= 0.03125f * 1.44269504088896f;
  w3[o] = f2bf(v);
}

// ---------------- QKV projection v9: decoupled x stream, x-resident LDS ----------------
// 512 blocks x 256 threads (4 waves), 64 rows/block (16/wave), 4 K-phases of 256.
// Per phase: wave streams its 16 rows x 1KB CONTIGUOUSLY into private swizzled LDS
// (rolling 8-load window, in-order vmcnt ladder, NO barriers), then 4 K-steps of
// pure LDS+MFMA with W double-buffered via global_load_lds + vmcnt(6).
// LDS 80KB -> 2 blocks/CU: one block streams while the other computes.
__global__ __launch_bounds__(256, 2) void qkv_kernel(const float* __restrict__ x,
                                                     const unsigned short* __restrict__ w3,
                                                     unsigned short* __restrict__ kb,
                                                     unsigned short* __restrict__ qb,
                                                     unsigned short* __restrict__ vb) {
  __shared__ __align__(16) unsigned short xls[16384];   // 4 waves x [16][256] swizzled bf16
  __shared__ __align__(16) unsigned short wl[2 * 12288];

  const int tid = threadIdx.x;
  const int lane = tid & 63;
  const int w = tid >> 6;
  const int l15 = lane & 15, lh = lane >> 4;
  const int r0 = blockIdx.x * 64;
  const int xw = w * 4096;
  const int abase = xw + l15 * 256;
  const int aswz = (l15 & 7) << 3;
  const int fb0 = l15 * 64 + ((lh ^ (l15 & 7)) << 3);
  const int fb1 = l15 * 64 + (((4 | lh) ^ (l15 & 7)) << 3);

  f32x4 acc[12];
#pragma unroll
  for (int i = 0; i < 12; ++i) acc[i] = {0.f, 0.f, 0.f, 0.f};

  float4 xq[8];   // 8-row rolling window; all indices compile-time constants

#define SB __builtin_amdgcn_sched_barrier(0)

#define XISSUE(R) xq[(R) & 7] = *(const float4*)(xb + (size_t)(R) * C_ + lane * 4)

#define XPROC(R, VM)                                                                   \
  do {                                                                                 \
    SB;                                                                                \
    asm volatile("s_waitcnt vmcnt(" #VM ")" ::: "memory");                             \
    SB;                                                                                \
    ushort4 h4_;                                                                       \
    h4_.x = f2bf(xq[(R) & 7].x); h4_.y = f2bf(xq[(R) & 7].y);                          \
    h4_.z = f2bf(xq[(R) & 7].z); h4_.w = f2bf(xq[(R) & 7].w);                          \
    *(ushort4*)&xls[xw + (R) * 256 + ((lane * 4) ^ (((R) & 7) << 3))] = h4_;           \
  } while (0)

  // producer loop for one 256-wide K-phase: 16 contiguous 1KB loads, ladder waits
#define XPRO(H)                                                                        \
  do {                                                                                 \
    const float* xb = x + (size_t)(r0 + w * 16) * C_ + (H) * 256;                      \
    XISSUE(0); XISSUE(1); XISSUE(2); XISSUE(3);                                        \
    XISSUE(4); XISSUE(5); XISSUE(6); XISSUE(7);                                        \
    XPROC(0, 7); XISSUE(8);  XPROC(1, 7); XISSUE(9);                                   \
    XPROC(2, 7); XISSUE(10); XPROC(3, 7); XISSUE(11);                                  \
    XPROC(4, 7); XISSUE(12); XPROC(5, 7); XISSUE(13);                                  \
    XPROC(6, 7); XISSUE(14); XPROC(7, 7); XISSUE(15);                                  \
    XPROC(8, 7); XPROC(9, 6); XPROC(10, 5); XPROC(11, 4);                              \
    XPROC(12, 3); XPROC(13, 2); XPROC(14, 1); XPROC(15, 0);                            \
  } while (0)

#define STAGEW(KK, BUF)                                                                \
  do {                                                                                 \
    _Pragma("unroll")                                                                  \
    for (int i_ = 0; i_ < 6; ++i_) {                                                   \
      const int eo_ = ((w * 6 + i_) << 9) + lane * 8;                                  \
      __builtin_amdgcn_global_load_lds(                                                \
          (const __attribute__((address_space(1))) void*)(w3 + (KK) * 12288 + eo_),    \
          (__attribute__((address_space(3))) void*)&wl[(BUF) * 12288 + eo_],           \
          16, 0, 0);                                                                   \
    }                                                                                  \
  } while (0)

#define COMPUTE(CUR, KKL)                                                              \
  do {                                                                                 \
    _Pragma("unroll")                                                                  \
    for (int ks_ = 0; ks_ < 2; ++ks_) {                                                \
      const int kl_ = (KKL) * 64 + ks_ * 32 + lh * 8;                                  \
      bf16x8 a_ = *(const bf16x8*)&xls[abase + (kl_ ^ aswz)];                          \
      const int fb_ = ks_ ? fb1 : fb0;                                                 \
      _Pragma("unroll")                                                                \
      for (int cf_ = 0; cf_ < 12; ++cf_) {                                             \
        bf16x8 b_ = *(const bf16x8*)&wl[(CUR) * 12288 + cf_ * 1024 + fb_];             \
        acc[cf_] = __builtin_amdgcn_mfma_f32_16x16x32_bf16(a_, b_, acc[cf_], 0, 0, 0); \
      }                                                                                \
    }                                                                                  \
  } while (0)

#define KSTEP(KKG, VM)                                                                 \
  do {                                                                                 \
    __syncthreads();                        /* all waves done reading wl[cur^1] */     \
    if ((KKG) < 15) STAGEW((KKG) + 1, ((KKG) + 1) & 1);                                \
    SB;                                                                                \
    asm volatile("s_waitcnt vmcnt(" #VM ")" ::: "memory");                             \
    SB;                                                                                \
    __builtin_amdgcn_s_barrier();           /* W(KKG) landed for every wave */         \
    COMPUTE((KKG) & 1, (KKG) & 3);                                                     \
  } while (0)

  // phase 0: stream x, then stage W(0)
  XPRO(0);
  STAGEW(0, 0);
  KSTEP(0, 6);  KSTEP(1, 6);  KSTEP(2, 6);  KSTEP(3, 6);
  XPRO(1);      // W(4) (staged during KSTEP(3)) lands under this stream
  KSTEP(4, 6);  KSTEP(5, 6);  KSTEP(6, 6);  KSTEP(7, 6);
  XPRO(2);
  KSTEP(8, 6);  KSTEP(9, 6);  KSTEP(10, 6); KSTEP(11, 6);
  XPRO(3);
  KSTEP(12, 6); KSTEP(13, 6); KSTEP(14, 6); KSTEP(15, 0);

#undef KSTEP
#undef COMPUTE
#undef STAGEW
#undef XPRO
#undef XPROC
#undef XISSUE
#undef SB

  // epilogue: C/D layout col=lane&15, row=(lane>>4)*4+rr (scales pre-folded)
#pragma unroll
  for (int cf = 0; cf < 4; ++cf) {
    int col = cf * 16 + l15;
#pragma unroll
    for (int r = 0; r < 4; ++r) {
      size_t row = (size_t)(r0 + w * 16 + lh * 4 + r);
      kb[row * HD_ + col] = f2bf(acc[cf][r]);
      qb[row * HD_ + col] = f2bf(acc[4 + cf][r]);
      vb[row * HD_ + col] = f2bf(acc[8 + cf][r]);
    }
  }
}

// ---------------- flash attention v2 (unchanged from round 4) ----------------
__global__ __launch_bounds__(256) void attn_kernel(const unsigned short* __restrict__ kb,
                                                   const unsigned short* __restrict__ qb,
                                                   const unsigned short* __restrict__ vb,
                                                   float* __restrict__ out) {
  __shared__ __align__(16) unsigned short q_lds[2][64 * 72];
  __shared__ __align__(16) unsigned short v_lds[2][64 * 72];
  __shared__ __align__(16) unsigned short p_lds[64 * 72];

  const int tid = threadIdx.x;
  const int lane = tid & 63;
  const int w = tid >> 6;
  const int bid = blockIdx.x;
  const int idx = bid >> 4;
  const int jt = (idx < 16) ? (31 - idx) : (idx - 16);
  const int b = bid & 15;
  const int t0 = jt * 64;
  const int l15 = lane & 15;
  const int lh = lane >> 4;
  const size_t base = (size_t)b * T_ * HD_;

  const int qrow = tid >> 3, qc8 = tid & 7;
  const int vss = tid & 63, vd0 = (tid >> 6) * 8;

  bf16x8 kf[2];
#pragma unroll
  for (int ks = 0; ks < 2; ++ks)
    kf[ks] = *reinterpret_cast<const bf16x8*>(
        &kb[base + (size_t)(t0 + w * 16 + l15) * HD_ + ks * 32 + lh * 8]);

  bf16x8 qr0, qr1, vr0, vr1;
  qr0 = *reinterpret_cast<const bf16x8*>(&qb[base + (size_t)qrow * HD_ + qc8 * 8]);
  qr1 = *reinterpret_cast<const bf16x8*>(&qb[base + (size_t)(qrow + 32) * HD_ + qc8 * 8]);
  vr0 = *reinterpret_cast<const bf16x8*>(&vb[base + (size_t)vss * HD_ + vd0]);
  vr1 = *reinterpret_cast<const bf16x8*>(&vb[base + (size_t)vss * HD_ + vd0 + 32]);

  f32x4 o[4];
#pragma unroll
  for (int i = 0; i < 4; ++i) o[i] = {0.f, 0.f, 0.f, 0.f};
  float mrun[4], lrun[4];
#pragma unroll
  for (int r = 0; r < 4; ++r) { mrun[r] = -1e30f; lrun[r] = 0.f; }

  for (int j = 0; j <= jt; ++j) {
    const int buf = j & 1;
    *reinterpret_cast<bf16x8*>(&q_lds[buf][qrow * 72 + qc8 * 8]) = qr0;
    *reinterpret_cast<bf16x8*>(&q_lds[buf][(qrow + 32) * 72 + qc8 * 8]) = qr1;
#pragma unroll
    for (int jj = 0; jj < 8; ++jj) v_lds[buf][(vd0 + jj) * 72 + vss] = (unsigned short)vr0[jj];
#pragma unroll
    for (int jj = 0; jj < 8; ++jj) v_lds[buf][(vd0 + 32 + jj) * 72 + vss] = (unsigned short)vr1[jj];
    __syncthreads();

    if (j < jt) {
      const size_t sb = base + (size_t)(j + 1) * 64 * HD_;
      qr0 = *reinterpret_cast<const bf16x8*>(&qb[sb + (size_t)qrow * HD_ + qc8 * 8]);
      qr1 = *reinterpret_cast<const bf16x8*>(&qb[sb + (size_t)(qrow + 32) * HD_ + qc8 * 8]);
      vr0 = *reinterpret_cast<const bf16x8*>(&vb[sb + (size_t)vss * HD_ + vd0]);
      vr1 = *reinterpret_cast<const bf16x8*>(&vb[sb + (size_t)vss * HD_ + vd0 + 32]);
    }
    __builtin_amdgcn_sched_barrier(0);

    f32x4 sf[4];
#pragma unroll
    for (int cf = 0; cf < 4; ++cf) sf[cf] = {0.f, 0.f, 0.f, 0.f};
    __builtin_amdgcn_s_setprio(1);
#pragma unroll
    for (int ks = 0; ks < 2; ++ks) {
#pragma unroll
      for (int cf = 0; cf < 4; ++cf) {
        bf16x8 bq = *reinterpret_cast<const bf16x8*>(&q_lds[buf][(cf * 16 + l15) * 72 + ks * 32 + lh * 8]);
        sf[cf] = __builtin_amdgcn_mfma_f32_16x16x32_bf16(kf[ks], bq, sf[cf], 0, 0, 0);
      }
    }
    __builtin_amdgcn_s_setprio(0);

    const bool diag = (j == jt);
    const int s0 = j * 64;
    float pv[4][4];
#pragma unroll
    for (int r = 0; r < 4; ++r) {
      const int tg = t0 + w * 16 + lh * 4 + r;
      float pm = -1e30f;
#pragma unroll
      for (int cf = 0; cf < 4; ++cf) {
        float v = sf[cf][r];
        if (diag && (s0 + cf * 16 + l15) > tg) v = -1e30f;
        pv[cf][r] = v;
        pm = fmaxf(pm, v);
      }
      pm = fmaxf(pm, __shfl_xor(pm, 1));
      pm = fmaxf(pm, __shfl_xor(pm, 2));
      pm = fmaxf(pm, __shfl_xor(pm, 4));
      pm = fmaxf(pm, __shfl_xor(pm, 8));
      float mn = fmaxf(mrun[r], pm);
      float scl = exp2f(mrun[r] - mn);
      mrun[r] = mn;
      float rs = 0.f;
#pragma unroll
      for (int cf = 0; cf < 4; ++cf) {
        float e = exp2f(pv[cf][r] - mn);
        pv[cf][r] = e;
        rs += e;
      }
      rs += __shfl_xor(rs, 1);
      rs += __shfl_xor(rs, 2);
      rs += __shfl_xor(rs, 4);
      rs += __shfl_xor(rs, 8);
      lrun[r] = lrun[r] * scl + rs;
#pragma unroll
      for (int df = 0; df < 4; ++df) o[df][r] *= scl;
    }
#pragma unroll
    for (int cf = 0; cf < 4; ++cf)
#pragma unroll
      for (int r = 0; r < 4; ++r)
        p_lds[(w * 16 + lh * 4 + r) * 72 + cf * 16 + l15] = f2bf(pv[cf][r]);

    __builtin_amdgcn_s_setprio(1);
#pragma unroll
    for (int ks = 0; ks < 2; ++ks) {
      bf16x8 pa = *reinterpret_cast<const bf16x8*>(&p_lds[(w * 16 + l15) * 72 + ks * 32 + lh * 8]);
#pragma unroll
      for (int df = 0; df < 4; ++df) {
        bf16x8 bv = *reinterpret_cast<const bf16x8*>(&v_lds[buf][(df * 16 + l15) * 72 + ks * 32 + lh * 8]);
        o[df] = __builtin_amdgcn_mfma_f32_16x16x32_bf16(pa, bv, o[df], 0, 0, 0);
      }
    }
    __builtin_amdgcn_s_setprio(0);
  }

#pragma unroll
  for (int r = 0; r < 4; ++r) {
    float inv = 1.f / lrun[r];
    int row = t0 + w * 16 + lh * 4 + r;
#pragma unroll
    for (int df = 0; df < 4; ++df)
      out[base + (size_t)row * HD_ + df * 16 + l15] = o[df][r] * inv;
  }
}

extern "C" void kernel_launch(void* const* d_in, const int* in_sizes, int n_in,
                              void* d_out, int out_size, void* d_ws, size_t ws_size,
                              hipStream_t stream) {
  const float* x  = (const float*)d_in[0];
  const float* Wk = (const float*)d_in[1];
  const float* Wq = (const float*)d_in[2];
  const float* Wv = (const float*)d_in[3];
  float* out = (float*)d_out;

  char* ws = (char*)d_ws;
  unsigned short* w3 = (unsigned short*)ws;                                  // 384 KB
  unsigned short* kb = (unsigned short*)(ws + 524288);                       // 4 MB
  unsigned short* qb = (unsigned short*)(ws + 524288 + 4 * 1024 * 1024);     // 4 MB
  unsigned short* vb = (unsigned short*)(ws + 524288 + 8 * 1024 * 1024);     // 4 MB

  hipLaunchKernelGGL(wconv_kernel, dim3(768), dim3(256), 0, stream, Wk, Wq, Wv, w3);
  hipLaunchKernelGGL(qkv_kernel, dim3(512), dim3(256), 0, stream, x, w3, kb, qb, vb);
  hipLaunchKernelGGL(attn_kernel, dim3(512), dim3(256), 0, stream, kb, qb, vb, out);
}

// Round 12
// 94.237 us; speedup vs baseline: 1.0339x; 1.0339x over previous
//
#include <hip/hip_runtime.h>
#include <hip/hip_bf16.h>

#define B_ 16
#define T_ 2048
#define C_ 1024
#define HD_ 64

typedef __attribute__((ext_vector_type(8))) short bf16x8;
typedef __attribute__((ext_vector_type(4))) float f32x4;

__device__ __forceinline__ unsigned short f2bf(float f) {
  return __builtin_bit_cast(unsigned short, __float2bfloat16(f));
}

// ---- W convert: per-K-step tiles w3[kk][n] (kk=0..15, 24KB tiles) ----
// n: row = n>>6 (192 rows = output col), chunk c=(n>>3)&7, e=n&7.
// Logical k = kk*64 + ((c ^ (row&7))*8 + e); m = row>>6, d = row&63.
// Scale 1/sqrt(C)*log2(e) folded into Wk -> scores in exp2 domain.
__global__ void wconv_kernel(const float* __restrict__ Wk, const float* __restrict__ Wq,
                             const float* __restrict__ Wv, unsigned short* __restrict__ w3) {
  int o = blockIdx.x * 256 + threadIdx.x;   // 16*12288 = 196608 total
  if (o >= 16 * 12288) return;
  int kk = o / 12288;
  int n = o - kk * 12288;
  int row = n >> 6;
  int c = (n >> 3) & 7;
  int e = n & 7;
  int k = kk * 64 + (((c ^ (row & 7)) << 3) | e);
  int m = row >> 6, d = row & 63;
  const float* W = (m == 0) ? Wk : (m == 1) ? Wq : Wv;
  float v = W[k * HD_ + d];
  if (m == 0) v *= 0.03125f * 1.44269504088896f;
  w3[o] = f2bf(v);
}

// ---------------- QKV projection v10: depth-5 W ring, never-drained x queue ----------------
// 256 blocks x 512 threads (8 waves), 128 rows/block, 192 cols, BK=64 (16 steps).
// W: ring of 6 x 24KB LDS buffers, staged 5 steps ahead via global_load_lds.
// x: depth-2 prefetch, 3 rotating register sets. Per step: {4 x-loads, vmcnt(14),
// barrier, 3 W-stage, 24 MFMA}. Steady-state waits hit the x-BW floor, not latency.
__global__ __launch_bounds__(512, 2) void qkv_kernel(const float* __restrict__ x,
                                                     const unsigned short* __restrict__ w3,
                                                     unsigned short* __restrict__ kb,
                                                     unsigned short* __restrict__ qb,
                                                     unsigned short* __restrict__ vb) {
  __shared__ __align__(16) unsigned short wl[6 * 12288];   // 144 KB ring

  const int tid = threadIdx.x;
  const int lane = tid & 63;
  const int w = tid >> 6;            // 8 waves
  const int l15 = lane & 15, lh = lane >> 4;
  const int r0 = blockIdx.x * 128;

  const float* xp = x + (size_t)(r0 + w * 16 + l15) * C_ + lh * 8;
  // frag read offsets: row l15 (128B stride), chunk^(l15&7) swizzle; +cf*1024 per frag
  const int fb0 = l15 * 64 + ((lh ^ (l15 & 7)) << 3);
  const int fb1 = l15 * 64 + (((4 | lh) ^ (l15 & 7)) << 3);

  f32x4 acc[12];
#pragma unroll
  for (int i = 0; i < 12; ++i) acc[i] = {0.f, 0.f, 0.f, 0.f};

  float4 xr0[4], xr1[4], xr2[4];   // 3 rotating x sets (all indices static)

#define STAGE(KK)                                                                    \
  do {                                                                               \
    _Pragma("unroll")                                                                \
    for (int i_ = 0; i_ < 3; ++i_) {                                                 \
      const int eo_ = ((w * 3 + i_) << 9) + lane * 8;   /* ushort offset in tile */  \
      __builtin_amdgcn_global_load_lds(                                              \
          (const __attribute__((address_space(1))) void*)(w3 + (KK) * 12288 + eo_),  \
          (__attribute__((address_space(3))) void*)&wl[((KK) % 6) * 12288 + eo_],    \
          16, 0, 0);                                                                 \
    }                                                                                \
  } while (0)

#define XLOAD(XR, KK) do { const float* p_ = xp + (KK) * 64;                   \
    XR[0] = *(const float4*)(p_);      XR[1] = *(const float4*)(p_ + 4);       \
    XR[2] = *(const float4*)(p_ + 32); XR[3] = *(const float4*)(p_ + 36); } while (0)

#define COMPUTE(S, XR)                                                               \
  do {                                                                               \
    const unsigned short* wb_ = &wl[((S) % 6) * 12288];                              \
    bf16x8 a0 = cvt8_(XR[0], XR[1]);                                                 \
    bf16x8 a1 = cvt8_(XR[2], XR[3]);                                                 \
    _Pragma("unroll")                                                                \
    for (int f_ = 0; f_ < 12; ++f_) {                                                \
      bf16x8 b0 = *(const bf16x8*)&wb_[f_ * 1024 + fb0];                             \
      acc[f_] = __builtin_amdgcn_mfma_f32_16x16x32_bf16(a0, b0, acc[f_], 0, 0, 0);   \
      bf16x8 b1 = *(const bf16x8*)&wb_[f_ * 1024 + fb1];                             \
      acc[f_] = __builtin_amdgcn_mfma_f32_16x16x32_bf16(a1, b1, acc[f_], 0, 0, 0);   \
    }                                                                                \
  } while (0)

#define SB __builtin_amdgcn_sched_barrier(0)

  // local cvt helper (macro-safe)
#define cvt8_(A, Bv) ({ bf16x8 r_;                                              \
    r_[0] = (short)f2bf((A).x); r_[1] = (short)f2bf((A).y);                     \
    r_[2] = (short)f2bf((A).z); r_[3] = (short)f2bf((A).w);                     \
    r_[4] = (short)f2bf((Bv).x); r_[5] = (short)f2bf((Bv).y);                   \
    r_[6] = (short)f2bf((Bv).z); r_[7] = (short)f2bf((Bv).w); r_; })

// per step S: load x(S+2), wait (x(S) + W(S) landed; 14 newer stay in flight),
// barrier (ring safety), stage W(S+5), compute.
#define ITER(S, XCUR, XPRE, VM)                                    \
  do {                                                             \
    if ((S) <= 13) { XLOAD(XPRE, (S) + 2); }                       \
    SB;                                                            \
    asm volatile("s_waitcnt vmcnt(" #VM ")" ::: "memory");         \
    SB;                                                            \
    __builtin_amdgcn_s_barrier();                                  \
    if ((S) <= 10) STAGE((S) + 5);                                 \
    SB;                                                            \
    COMPUTE(S, XCUR);                                              \
  } while (0)

  // prologue mimicking steps -5..-1: W0,W1,W2, [x0,W3], [x1,W4]
  STAGE(0); STAGE(1); STAGE(2);
  SB;
  XLOAD(xr0, 0);
  SB;
  STAGE(3);
  SB;
  XLOAD(xr1, 1);
  SB;
  STAGE(4);
  SB;

  ITER(0, xr0, xr2, 14);
  ITER(1, xr1, xr0, 14);
  ITER(2, xr2, xr1, 14);
  ITER(3, xr0, xr2, 14);
  ITER(4, xr1, xr0, 14);
  ITER(5, xr2, xr1, 14);
  ITER(6, xr0, xr2, 14);
  ITER(7, xr1, xr0, 14);
  ITER(8, xr2, xr1, 14);
  ITER(9, xr0, xr2, 14);
  ITER(10, xr1, xr0, 14);
  ITER(11, xr2, xr1, 14);
  ITER(12, xr0, xr2, 11);
  ITER(13, xr1, xr0, 8);
  ITER(14, xr2, xr1, 4);
  ITER(15, xr0, xr2, 0);

#undef ITER
#undef cvt8_
#undef SB
#undef COMPUTE
#undef XLOAD
#undef STAGE

  // epilogue: C/D layout col=lane&15, row=(lane>>4)*4+rr (scales pre-folded)
#pragma unroll
  for (int cf = 0; cf < 4; ++cf) {
    int col = cf * 16 + l15;
#pragma unroll
    for (int r = 0; r < 4; ++r) {
      size_t row = (size_t)(r0 + w * 16 + lh * 4 + r);
      kb[row * HD_ + col] = f2bf(acc[cf][r]);
      qb[row * HD_ + col] = f2bf(acc[4 + cf][r]);
      vb[row * HD_ + col] = f2bf(acc[8 + cf][r]);
    }
  }
}

// ---------------- flash attention v2 (unchanged from round 4) ----------------
__global__ __launch_bounds__(256) void attn_kernel(const unsigned short* __restrict__ kb,
                                                   const unsigned short* __restrict__ qb,
                                                   const unsigned short* __restrict__ vb,
                                                   float* __restrict__ out) {
  __shared__ __align__(16) unsigned short q_lds[2][64 * 72];
  __shared__ __align__(16) unsigned short v_lds[2][64 * 72];
  __shared__ __align__(16) unsigned short p_lds[64 * 72];

  const int tid = threadIdx.x;
  const int lane = tid & 63;
  const int w = tid >> 6;
  const int bid = blockIdx.x;
  const int idx = bid >> 4;
  const int jt = (idx < 16) ? (31 - idx) : (idx - 16);
  const int b = bid & 15;
  const int t0 = jt * 64;
  const int l15 = lane & 15;
  const int lh = lane >> 4;
  const size_t base = (size_t)b * T_ * HD_;

  const int qrow = tid >> 3, qc8 = tid & 7;
  const int vss = tid & 63, vd0 = (tid >> 6) * 8;

  bf16x8 kf[2];
#pragma unroll
  for (int ks = 0; ks < 2; ++ks)
    kf[ks] = *reinterpret_cast<const bf16x8*>(
        &kb[base + (size_t)(t0 + w * 16 + l15) * HD_ + ks * 32 + lh * 8]);

  bf16x8 qr0, qr1, vr0, vr1;
  qr0 = *reinterpret_cast<const bf16x8*>(&qb[base + (size_t)qrow * HD_ + qc8 * 8]);
  qr1 = *reinterpret_cast<const bf16x8*>(&qb[base + (size_t)(qrow + 32) * HD_ + qc8 * 8]);
  vr0 = *reinterpret_cast<const bf16x8*>(&vb[base + (size_t)vss * HD_ + vd0]);
  vr1 = *reinterpret_cast<const bf16x8*>(&vb[base + (size_t)vss * HD_ + vd0 + 32]);

  f32x4 o[4];
#pragma unroll
  for (int i = 0; i < 4; ++i) o[i] = {0.f, 0.f, 0.f, 0.f};
  float mrun[4], lrun[4];
#pragma unroll
  for (int r = 0; r < 4; ++r) { mrun[r] = -1e30f; lrun[r] = 0.f; }

  for (int j = 0; j <= jt; ++j) {
    const int buf = j & 1;
    *reinterpret_cast<bf16x8*>(&q_lds[buf][qrow * 72 + qc8 * 8]) = qr0;
    *reinterpret_cast<bf16x8*>(&q_lds[buf][(qrow + 32) * 72 + qc8 * 8]) = qr1;
#pragma unroll
    for (int jj = 0; jj < 8; ++jj) v_lds[buf][(vd0 + jj) * 72 + vss] = (unsigned short)vr0[jj];
#pragma unroll
    for (int jj = 0; jj < 8; ++jj) v_lds[buf][(vd0 + 32 + jj) * 72 + vss] = (unsigned short)vr1[jj];
    __syncthreads();

    if (j < jt) {
      const size_t sb = base + (size_t)(j + 1) * 64 * HD_;
      qr0 = *reinterpret_cast<const bf16x8*>(&qb[sb + (size_t)qrow * HD_ + qc8 * 8]);
      qr1 = *reinterpret_cast<const bf16x8*>(&qb[sb + (size_t)(qrow + 32) * HD_ + qc8 * 8]);
      vr0 = *reinterpret_cast<const bf16x8*>(&vb[sb + (size_t)vss * HD_ + vd0]);
      vr1 = *reinterpret_cast<const bf16x8*>(&vb[sb + (size_t)vss * HD_ + vd0 + 32]);
    }
    __builtin_amdgcn_sched_barrier(0);

    f32x4 sf[4];
#pragma unroll
    for (int cf = 0; cf < 4; ++cf) sf[cf] = {0.f, 0.f, 0.f, 0.f};
    __builtin_amdgcn_s_setprio(1);
#pragma unroll
    for (int ks = 0; ks < 2; ++ks) {
#pragma unroll
      for (int cf = 0; cf < 4; ++cf) {
        bf16x8 bq = *reinterpret_cast<const bf16x8*>(&q_lds[buf][(cf * 16 + l15) * 72 + ks * 32 + lh * 8]);
        sf[cf] = __builtin_amdgcn_mfma_f32_16x16x32_bf16(kf[ks], bq, sf[cf], 0, 0, 0);
      }
    }
    __builtin_amdgcn_s_setprio(0);

    const bool diag = (j == jt);
    const int s0 = j * 64;
    float pv[4][4];
#pragma unroll
    for (int r = 0; r < 4; ++r) {
      const int tg = t0 + w * 16 + lh * 4 + r;
      float pm = -1e30f;
#pragma unroll
      for (int cf = 0; cf < 4; ++cf) {
        float v = sf[cf][r];
        if (diag && (s0 + cf * 16 + l15) > tg) v = -1e30f;
        pv[cf][r] = v;
        pm = fmaxf(pm, v);
      }
      pm = fmaxf(pm, __shfl_xor(pm, 1));
      pm = fmaxf(pm, __shfl_xor(pm, 2));
      pm = fmaxf(pm, __shfl_xor(pm, 4));
      pm = fmaxf(pm, __shfl_xor(pm, 8));
      float mn = fmaxf(mrun[r], pm);
      float scl = exp2f(mrun[r] - mn);
      mrun[r] = mn;
      float rs = 0.f;
#pragma unroll
      for (int cf = 0; cf < 4; ++cf) {
        float e = exp2f(pv[cf][r] - mn);
        pv[cf][r] = e;
        rs += e;
      }
      rs += __shfl_xor(rs, 1);
      rs += __shfl_xor(rs, 2);
      rs += __shfl_xor(rs, 4);
      rs += __shfl_xor(rs, 8);
      lrun[r] = lrun[r] * scl + rs;
#pragma unroll
      for (int df = 0; df < 4; ++df) o[df][r] *= scl;
    }
#pragma unroll
    for (int cf = 0; cf < 4; ++cf)
#pragma unroll
      for (int r = 0; r < 4; ++r)
        p_lds[(w * 16 + lh * 4 + r) * 72 + cf * 16 + l15] = f2bf(pv[cf][r]);

    __builtin_amdgcn_s_setprio(1);
#pragma unroll
    for (int ks = 0; ks < 2; ++ks) {
      bf16x8 pa = *reinterpret_cast<const bf16x8*>(&p_lds[(w * 16 + l15) * 72 + ks * 32 + lh * 8]);
#pragma unroll
      for (int df = 0; df < 4; ++df) {
        bf16x8 bv = *reinterpret_cast<const bf16x8*>(&v_lds[buf][(df * 16 + l15) * 72 + ks * 32 + lh * 8]);
        o[df] = __builtin_amdgcn_mfma_f32_16x16x32_bf16(pa, bv, o[df], 0, 0, 0);
      }
    }
    __builtin_amdgcn_s_setprio(0);
  }

#pragma unroll
  for (int r = 0; r < 4; ++r) {
    float inv = 1.f / lrun[r];
    int row = t0 + w * 16 + lh * 4 + r;
#pragma unroll
    for (int df = 0; df < 4; ++df)
      out[base + (size_t)row * HD_ + df * 16 + l15] = o[df][r] * inv;
  }
}

extern "C" void kernel_launch(void* const* d_in, const int* in_sizes, int n_in,
                              void* d_out, int out_size, void* d_ws, size_t ws_size,
                              hipStream_t stream) {
  const float* x  = (const float*)d_in[0];
  const float* Wk = (const float*)d_in[1];
  const float* Wq = (const float*)d_in[2];
  const float* Wv = (const float*)d_in[3];
  float* out = (float*)d_out;

  char* ws = (char*)d_ws;
  unsigned short* w3 = (unsigned short*)ws;                                  // 384 KB
  unsigned short* kb = (unsigned short*)(ws + 524288);                       // 4 MB
  unsigned short* qb = (unsigned short*)(ws + 524288 + 4 * 1024 * 1024);     // 4 MB
  unsigned short* vb = (unsigned short*)(ws + 524288 + 8 * 1024 * 1024);     // 4 MB

  hipLaunchKernelGGL(wconv_kernel, dim3(768), dim3(256), 0, stream, Wk, Wq, Wv, w3);
  hipLaunchKernelGGL(qkv_kernel, dim3(256), dim3(512), 0, stream, x, w3, kb, qb, vb);
  hipLaunchKernelGGL(attn_kernel, dim3(512), dim3(256), 0, stream, kb, qb, vb, out);
}